// Round 9
// baseline (984.151 us; speedup 1.0000x reference)
//
#include <hip/hip_runtime.h>
#include <hip/hip_bf16.h>
#include <stdint.h>

#define B_ 8
#define C_ 512
#define S_ 2048
#define L_ 8921
#define LTILE 128
#define NLT 70            // ceil(L/128); tail rows clamped, never read by finalize
#define BS 128            // s-rows per round-group (one acc lifetime)
#define SCHUNK 512        // s range per workgroup
#define NSC 4             // S / SCHUNK
#define BK 128            // k per round (4 ksteps of 32)
#define ROUNDS 16         // 4 s-tiles * 4 k-rounds

#define NW4 ((L_ * C_) / 4)          // 1,141,888 float4 quads per W array
#define NWBLK ((NW4 + 255) / 256)    // 4461 blocks per W array
#define NEBLK (B_ * 32 * 8)          // 2048 blocks for the E transpose

using f32x4 = __attribute__((ext_vector_type(4))) float;
using s16x8 = __attribute__((ext_vector_type(8))) short;   // 8 bf16 = 4 VGPRs

static __device__ __forceinline__ unsigned short f2bf(float f) {
    union { float f; uint32_t u; } a; a.f = f;
    uint32_t u = a.u;
    return (unsigned short)((u + 0x7fffu + ((u >> 16) & 1u)) >> 16);   // RTNE
}

// ---- fused prep: encoded transpose->bf16 + both W cvt in ONE launch ----
__global__ void prep(const float* __restrict__ enc, unsigned short* __restrict__ ebt,
                     const float* __restrict__ Wa, unsigned short* __restrict__ waBf,
                     const float* __restrict__ Wc, unsigned short* __restrict__ wcBf) {
    __shared__ float tile[64][65];
    const int x = blockIdx.x;
    const int t = threadIdx.x;

    if (x < NEBLK) {
        // ---- encoded (B,C,S) fp32 -> Ebt (B,S,C) bf16, tiled transpose ----
        int ct = (x & 7) * 64;          // C/64 = 8
        int st = ((x >> 3) & 31) * 64;  // S/64 = 32
        int b  = x >> 8;
        const float* src = enc + (size_t)b * C_ * S_;
        #pragma unroll
        for (int it = 0; it < 16; ++it) {
            int idx = it * 256 + t;
            int rc = idx >> 6, rs = idx & 63;
            tile[rc][rs] = src[(size_t)(ct + rc) * S_ + st + rs];
        }
        __syncthreads();
        unsigned short* dst = ebt + (size_t)b * S_ * C_;
        // vectorized store side: each thread writes 4 consecutive c (8B)
        #pragma unroll
        for (int it = 0; it < 4; ++it) {
            int idx = it * 256 + t;
            int rs  = idx >> 4;           // 0..63
            int rc4 = (idx & 15) << 2;    // 0,4,..,60
            ushort4 o;
            o.x = f2bf(tile[rc4 + 0][rs]);
            o.y = f2bf(tile[rc4 + 1][rs]);
            o.z = f2bf(tile[rc4 + 2][rs]);
            o.w = f2bf(tile[rc4 + 3][rs]);
            *(ushort4*)(dst + (size_t)(st + rs) * C_ + ct + rc4) = o;
        }
    } else {
        // ---- fp32 -> bf16 elementwise for W_attn / W_cls ----
        int wb = x - NEBLK;
        const float* src;
        unsigned short* dst;
        if (wb < NWBLK) { src = Wa; dst = waBf; }
        else            { src = Wc; dst = wcBf; wb -= NWBLK; }
        int i = wb * 256 + t;
        if (i < NW4) {
            float4 v = ((const float4*)src)[i];
            ushort4 o;
            o.x = f2bf(v.x); o.y = f2bf(v.y); o.z = f2bf(v.z); o.w = f2bf(v.w);
            ((ushort4*)dst)[i] = o;
        }
    }
}

// ---- fused scores/softmax/value main kernel ----
// R9: E-DIRECT structure. The fe B-fragment (16 rows x 64B, 16B/lane) is
// loaded straight from Ebt global memory -- per-lane address
// (row = nf*16 + (lane&15), k-bytes = (lane>>4)*16 within the kstep window)
// IS the MFMA B-operand layout, and Ebt (16MB) is L2/L3-resident with heavy
// cross-block reuse. This deletes the entire LDS path of R7/R8:
// no global_load_lds, no ds_read (was 25% of the round-slot), NO BARRIERS.
// Waves free-run; at 2 waves/SIMD, one wave's ~200cyc L2 fe-latency hides
// under the other wave's ~620cyc MFMA burst. sched_barrier(0) at kstep
// boundaries pins the unroller (stops hoisting all 32 fe loads -> spill).
// Same logical tiling as R7 (block=(lt,b,sc), wave owns 32 L-rows over the
// 128-s x 512-k range; BK=128, ROUNDS=16, epilogue every 4 rounds) -> the
// arithmetic, rounding, and output mapping are bit-identical to R7.
// Register envelope: acc 128 AGPR; fe 32 + wcur/wnxt 32 + addr ~15 VGPR.
__global__ __launch_bounds__(256, 2) void attn_main(
    const unsigned short* __restrict__ ebt,
    const unsigned short* __restrict__ wa,
    const unsigned short* __restrict__ wc,
    float* __restrict__ pnum, float* __restrict__ pden)
{
    const int tid  = threadIdx.x;
    const int lane = tid & 63;
    const int wave = tid >> 6;      // 0..3

    const int x  = blockIdx.x;
    const int lt = x >> 5;          // 32 consecutive blocks share one W tile
    const int rb = x & 31;
    const int b  = rb >> 2;
    const int sc = rb & 3;
    const int l0 = lt * LTILE;

    // per-lane W row offsets (element units), wave covers rows [wave*32, wave*32+32)
    int rowOff[2];
    #pragma unroll
    for (int mf = 0; mf < 2; ++mf) {
        int gl = l0 + wave * 32 + mf * 16 + (lane & 15);
        if (gl > L_ - 1) gl = L_ - 1;
        rowOff[mf] = gl * C_ + ((lane >> 4) << 3);
    }

    // E direct-read fragment base (element units):
    //   row  = sc*512 + (rr>>2)*128 + nf*16 + (lane&15)
    //   elem = (rr&3)*128 + ks*32 + (lane>>4)*8
    const unsigned short* feP = ebt + (size_t)b * S_ * C_
        + (size_t)(sc * SCHUNK + (lane & 15)) * C_ + ((lane >> 4) << 3);

    struct W4 { s16x8 a0, a1, c0, c1; };
    auto loadW = [&](int rr, int ks) -> W4 {
        const int co = ((rr & 3) << 7) + (ks << 5);
        W4 w;
        w.a0 = *(const s16x8*)(wa + rowOff[0] + co);
        w.a1 = *(const s16x8*)(wa + rowOff[1] + co);
        w.c0 = *(const s16x8*)(wc + rowOff[0] + co);
        w.c1 = *(const s16x8*)(wc + rowOff[1] + co);
        return w;
    };

    f32x4 accS[2][8], accV[2][8];
    #pragma unroll
    for (int mf = 0; mf < 2; ++mf)
        #pragma unroll
        for (int nf = 0; nf < 8; ++nf) {
            accS[mf][nf] = (f32x4){0.f, 0.f, 0.f, 0.f};
            accV[mf][nf] = (f32x4){0.f, 0.f, 0.f, 0.f};
        }
    float numAcc[2][4], denAcc[2][4];
    #pragma unroll
    for (int mf = 0; mf < 2; ++mf)
        #pragma unroll
        for (int r = 0; r < 4; ++r) { numAcc[mf][r] = 0.f; denAcc[mf][r] = 0.f; }

    W4 wcur = loadW(0, 0);

    for (int rr = 0; rr < ROUNDS; ++rr) {
        // element offset of this round's k-window within the s-tile's rows
        const int eOff = ((rr >> 2) << 16) + ((rr & 3) << 7);   // (rr>>2)*128*512 + (rr&3)*128

        #pragma unroll
        for (int ks = 0; ks < 4; ++ks) {
            // prefetch next kstep's W (or next round's kstep 0)
            W4 wnxt;
            if (ks < 3)                wnxt = loadW(rr, ks + 1);
            else if (rr + 1 < ROUNDS)  wnxt = loadW(rr + 1, 0);
            else                       wnxt = wcur;

            s16x8 fe[8];
            #pragma unroll
            for (int nf = 0; nf < 8; ++nf)
                fe[nf] = *(const s16x8*)(feP + eOff + nf * 8192 + ks * 32);

            __builtin_amdgcn_s_setprio(1);
            #pragma unroll
            for (int nf = 0; nf < 8; ++nf) {
                accS[0][nf] = __builtin_amdgcn_mfma_f32_16x16x32_bf16(wcur.a0, fe[nf], accS[0][nf], 0, 0, 0);
                accS[1][nf] = __builtin_amdgcn_mfma_f32_16x16x32_bf16(wcur.a1, fe[nf], accS[1][nf], 0, 0, 0);
                accV[0][nf] = __builtin_amdgcn_mfma_f32_16x16x32_bf16(wcur.c0, fe[nf], accV[0][nf], 0, 0, 0);
                accV[1][nf] = __builtin_amdgcn_mfma_f32_16x16x32_bf16(wcur.c1, fe[nf], accV[1][nf], 0, 0, 0);
            }
            __builtin_amdgcn_s_setprio(0);
            wcur = wnxt;
            // pin kstep boundary: stops the scheduler from hoisting later
            // ksteps' 8 fe loads above these MFMAs (register blow-up).
            __builtin_amdgcn_sched_barrier(0);
        }

        if ((rr & 3) == 3) {
            // softmax-accumulate epilogue for this 128-s tile
            // (scores ~N(0,0.45): |s|<~3.5, exp safe without max subtraction)
            #pragma unroll
            for (int mf = 0; mf < 2; ++mf)
                #pragma unroll
                for (int nf = 0; nf < 8; ++nf)
                    #pragma unroll
                    for (int r = 0; r < 4; ++r) {
                        float e = __expf(accS[mf][nf][r]);
                        denAcc[mf][r] += e;
                        numAcc[mf][r] += e * accV[mf][nf][r];
                        accS[mf][nf][r] = 0.f;
                        accV[mf][nf][r] = 0.f;
                    }
        }
    }

    // reduce the 16 s-columns spread over lane bits 0..3; each wave owns its
    // 32 L-rows completely (nf covered the full 128-s span) -> no LDS reduce.
    const size_t obase = ((size_t)((b * NLT + lt) * NSC + sc)) * LTILE;
    #pragma unroll
    for (int mf = 0; mf < 2; ++mf)
        #pragma unroll
        for (int r = 0; r < 4; ++r) {
            float n = numAcc[mf][r], d = denAcc[mf][r];
            n += __shfl_xor(n, 1);  d += __shfl_xor(d, 1);
            n += __shfl_xor(n, 2);  d += __shfl_xor(d, 2);
            n += __shfl_xor(n, 4);  d += __shfl_xor(d, 4);
            n += __shfl_xor(n, 8);  d += __shfl_xor(d, 8);
            if ((lane & 15) == 0) {
                int row = wave * 32 + mf * 16 + (lane >> 4) * 4 + r;
                pnum[obase + row] = n;
                pden[obase + row] = d;
            }
        }
}

// ---- combine s-chunk partials, divide, add b_cls ----
__global__ void finalize(const float* __restrict__ pnum, const float* __restrict__ pden,
                         const float* __restrict__ bcls, float* __restrict__ out) {
    int gid = blockIdx.x * 256 + threadIdx.x;
    if (gid >= B_ * L_) return;
    int b = gid / L_, l = gid - b * L_;
    int lt = l >> 7, row = l & 127;
    float n = 0.f, d = 0.f;
    #pragma unroll
    for (int s = 0; s < NSC; ++s) {
        size_t idx = ((size_t)((b * NLT + lt) * NSC + s)) * LTILE + row;
        n += pnum[idx];
        d += pden[idx];
    }
    out[gid] = n / d + bcls[l];
}

extern "C" void kernel_launch(void* const* d_in, const int* in_sizes, int n_in,
                              void* d_out, int out_size, void* d_ws, size_t ws_size,
                              hipStream_t stream) {
    (void)in_sizes; (void)n_in; (void)out_size; (void)ws_size;
    const float* enc  = (const float*)d_in[0];
    const float* Wa   = (const float*)d_in[1];
    // d_in[2] = b_attn: cancels in softmax over S — unused.
    const float* Wc   = (const float*)d_in[3];
    const float* bcls = (const float*)d_in[4];

    unsigned char* ws = (unsigned char*)d_ws;
    const size_t oEbt = 0;                          // B*S*C*2  = 16,777,216
    const size_t oWa  = oEbt + 16777216;            // L*C*2    =  9,135,104 (+pad)
    const size_t oWc  = oWa + 9136128;
    const size_t oPn  = oWc + 9136128;              // 2240*128*4 = 1,146,880
    const size_t oPd  = oPn + 1146880;              // total ~37.3 MB

    unsigned short* ebt  = (unsigned short*)(ws + oEbt);
    unsigned short* waBf = (unsigned short*)(ws + oWa);
    unsigned short* wcBf = (unsigned short*)(ws + oWc);
    float* pnum = (float*)(ws + oPn);
    float* pden = (float*)(ws + oPd);

    prep<<<NEBLK + 2 * NWBLK, 256, 0, stream>>>(enc, ebt, Wa, waBf, Wc, wcBf);
    attn_main<<<NLT * 32, 256, 0, stream>>>(ebt, waBf, wcBf, pnum, pden);
    finalize<<<(B_ * L_ + 255) / 256, 256, 0, stream>>>(pnum, pden, bcls, (float*)d_out);
}

// Round 10
// 454.269 us; speedup vs baseline: 2.1665x; 2.1665x over previous
//
#include <hip/hip_runtime.h>
#include <hip/hip_bf16.h>
#include <stdint.h>

#define B_ 8
#define C_ 512
#define S_ 2048
#define L_ 8921
#define LTILE 64          // L rows per block (2 halves of 32)
#define NLT 140           // ceil(L/64); tail rows clamped, never read by finalize
#define BS 128            // s-rows per round-group (one acc lifetime)
#define SCHUNK 512        // s range per workgroup
#define NSC 4             // S / SCHUNK
#define BK 64             // k per round (2 ksteps of 32)
#define ROUNDS 32         // 4 s-tiles * 8 k-rounds

#define NW4 ((L_ * C_) / 4)          // 1,141,888 float4 quads per W array
#define NWBLK ((NW4 + 255) / 256)    // 4461 blocks per W array
#define NEBLK (B_ * 32 * 8)          // 2048 blocks for the E transpose

using f32x4 = __attribute__((ext_vector_type(4))) float;
using s16x8 = __attribute__((ext_vector_type(8))) short;   // 8 bf16 = 4 VGPRs

static __device__ __forceinline__ unsigned short f2bf(float f) {
    union { float f; uint32_t u; } a; a.f = f;
    uint32_t u = a.u;
    return (unsigned short)((u + 0x7fffu + ((u >> 16) & 1u)) >> 16);   // RTNE
}
static __device__ __forceinline__ float bf2f(uint32_t h16) {
    union { uint32_t u; float f; } a; a.u = h16 << 16; return a.f;
}

// ---- fused prep: encoded transpose->bf16 + both W cvt in ONE launch ----
__global__ void prep(const float* __restrict__ enc, unsigned short* __restrict__ ebt,
                     const float* __restrict__ Wa, unsigned short* __restrict__ waBf,
                     const float* __restrict__ Wc, unsigned short* __restrict__ wcBf) {
    __shared__ float tile[64][65];
    const int x = blockIdx.x;
    const int t = threadIdx.x;

    if (x < NEBLK) {
        int ct = (x & 7) * 64;          // C/64 = 8
        int st = ((x >> 3) & 31) * 64;  // S/64 = 32
        int b  = x >> 8;
        const float* src = enc + (size_t)b * C_ * S_;
        #pragma unroll
        for (int it = 0; it < 16; ++it) {
            int idx = it * 256 + t;
            int rc = idx >> 6, rs = idx & 63;
            tile[rc][rs] = src[(size_t)(ct + rc) * S_ + st + rs];
        }
        __syncthreads();
        unsigned short* dst = ebt + (size_t)b * S_ * C_;
        #pragma unroll
        for (int it = 0; it < 4; ++it) {
            int idx = it * 256 + t;
            int rs  = idx >> 4;           // 0..63
            int rc4 = (idx & 15) << 2;    // 0,4,..,60
            ushort4 o;
            o.x = f2bf(tile[rc4 + 0][rs]);
            o.y = f2bf(tile[rc4 + 1][rs]);
            o.z = f2bf(tile[rc4 + 2][rs]);
            o.w = f2bf(tile[rc4 + 3][rs]);
            *(ushort4*)(dst + (size_t)(st + rs) * C_ + ct + rc4) = o;
        }
    } else {
        int wb = x - NEBLK;
        const float* src;
        unsigned short* dst;
        if (wb < NWBLK) { src = Wa; dst = waBf; }
        else            { src = Wc; dst = wcBf; wb -= NWBLK; }
        int i = wb * 256 + t;
        if (i < NW4) {
            float4 v = ((const float4*)src)[i];
            ushort4 o;
            o.x = f2bf(v.x); o.y = f2bf(v.y); o.z = f2bf(v.z); o.w = f2bf(v.w);
            ((ushort4*)dst)[i] = o;
        }
    }
}

// ---- fused scores/softmax/value main kernel ----
// R10: WAVE ROLE-SPECIALIZATION for 3-waves/SIMD occupancy.
// Each wave computes ONE GEMM (wave>>1: 0=scores via wa, 1=value via wc)
// for 32 L-rows x 128 s -> acc = 64 regs (was 128), W chain halves.
// Block = 4 waves (2S+2V) covering 64 L rows; grid = 140 x 32.
// E: R1's proven conflict-free 16KB tile (128s x 64k, 128B rows, chunk^(s&7)
// swizzle), double-buffered (32KB); per-round barrier with counted
// vmcnt(2) + lgkmcnt(0).
// Softmax handoff: at each s-group end (rr&7==7), S-wave h writes
// e=exp(accS) as bf16 to the 8KB e-buf half h (8 x ds_write_b128 per lane
// at lane*128 + (chunk^(lane&7))*16 -- conflict-optimal, same pattern as
// the E tile); den += e stays on the S-wave. V-wave h reads it at the TOP
// of the next round (overlapping stage glds latency), folds num += e*accV,
// zeroes accV. Ordering rides the round barrier (lgkmcnt(0) drains the
// ds_writes). Final group's V-fold runs post-loop after the last barrier.
// LDS: 32KB tile + 16KB e-buf = 48KB -> 3 blocks/CU (144KB).
// Register target: acc 64 + fe 32 + W chain 16 + addr/misc ~45 -> ~160 <= 170.
__global__ __launch_bounds__(256, 3) void attn_main(
    const unsigned short* __restrict__ ebt,
    const unsigned short* __restrict__ wa,
    const unsigned short* __restrict__ wc,
    float* __restrict__ pnum, float* __restrict__ pden)
{
    __shared__ __align__(16) unsigned char sE[49152];   // [0,32K) tile dbuf, [32K,48K) e-buf

    const int tid  = threadIdx.x;
    const int lane = tid & 63;
    const int wave = tid >> 6;      // 0..3
    const int h    = wave & 1;      // L-half within the block
    const int isV  = wave >> 1;     // 0 = scores (wa), 1 = value (wc)

    const int x  = blockIdx.x;
    const int lt = x >> 5;          // 32 consecutive blocks share one W tile
    const int rb = x & 31;
    const int b  = rb >> 2;
    const int sc = rb & 3;
    const int l0 = lt * LTILE;

    // per-lane W row offsets (element units); wave covers rows [h*32, h*32+32)
    int rowOff[2];
    #pragma unroll
    for (int mf = 0; mf < 2; ++mf) {
        int gl = l0 + h * 32 + mf * 16 + (lane & 15);
        if (gl > L_ - 1) gl = L_ - 1;
        rowOff[mf] = gl * C_ + ((lane >> 4) << 3);
    }
    const unsigned short* wsel = isV ? wc : wa;

    // E staging constants (R1's exact expressions)
    const size_t ebase = (size_t)b * S_ * C_;
    const int kgsrcE = (((lane & 7) ^ ((lane >> 3) & 7)) << 3);  // pre-swizzled src col
    // E frag read constants (R1's exact expressions)
    const int rowPart = (lane & 15) << 7;   // s_local * 128 bytes
    const int laneQ = lane >> 4;
    const int laneX = lane & 7;
    // e-buf base for this wave pair
    const int ebufB = 32768 + (h << 13);

    struct W2 { s16x8 r0, r1; };
    auto loadW = [&](int rr, int k) -> W2 {
        const int co = ((rr & 7) << 6) + (k << 5);
        W2 w;
        w.r0 = *(const s16x8*)(wsel + rowOff[0] + co);
        w.r1 = *(const s16x8*)(wsel + rowOff[1] + co);
        return w;
    };

    auto stageE = [&](int rr2) {
        const int kcol = (rr2 & 7) << 6;
        const int sBase = sc * SCHUNK + ((rr2 >> 3) << 7);   // s-tile*128
        unsigned char* dbase = sE + ((rr2 & 1) << 14);
        #pragma unroll
        for (int jj = 0; jj < 4; ++jj) {
            const int j = wave * 4 + jj;     // 0..15
            const int sg = sBase + j * 8 + (lane >> 3);
            const unsigned short* g = ebt + ebase + (size_t)sg * C_ + kcol + kgsrcE;
            __builtin_amdgcn_global_load_lds(
                (__attribute__((address_space(1))) void*)g,
                (__attribute__((address_space(3))) void*)(dbase + j * 1024),
                16, 0, 0);
        }
    };

    f32x4 acc[2][8];
    #pragma unroll
    for (int mf = 0; mf < 2; ++mf)
        #pragma unroll
        for (int nf = 0; nf < 8; ++nf)
            acc[mf][nf] = (f32x4){0.f, 0.f, 0.f, 0.f};
    float redAcc[2][4];   // den (S-waves) or num (V-waves)
    #pragma unroll
    for (int mf = 0; mf < 2; ++mf)
        #pragma unroll
        for (int r = 0; r < 4; ++r) redAcc[mf][r] = 0.f;

    // V-side fold of one s-group's e (reads e-buf, updates num, zeroes acc)
    auto vFold = [&]() {
        #pragma unroll
        for (int j = 0; j < 8; ++j) {
            uint4 q = *(const uint4*)(sE + ebufB + (lane << 7) + ((j ^ (lane & 7)) << 4));
            uint32_t wd[4] = {q.x, q.y, q.z, q.w};
            #pragma unroll
            for (int w2 = 0; w2 < 4; ++w2) {
                const int v0 = j * 8 + w2 * 2, v1 = v0 + 1;
                float e0 = bf2f(wd[w2] & 0xffffu);
                float e1 = bf2f(wd[w2] >> 16);
                redAcc[v0 >> 5][v0 & 3] += e0 * acc[v0 >> 5][(v0 >> 2) & 7][v0 & 3];
                redAcc[v1 >> 5][v1 & 3] += e1 * acc[v1 >> 5][(v1 >> 2) & 7][v1 & 3];
            }
        }
        #pragma unroll
        for (int mf = 0; mf < 2; ++mf)
            #pragma unroll
            for (int nf = 0; nf < 8; ++nf)
                #pragma unroll
                for (int r = 0; r < 4; ++r) acc[mf][nf][r] = 0.f;
    };

    // prologue: fill buffer 0, full drain once, then enter steady state
    stageE(0);
    W2 wcur = loadW(0, 0);
    asm volatile("s_waitcnt vmcnt(0)" ::: "memory");
    __builtin_amdgcn_s_barrier();
    __builtin_amdgcn_sched_barrier(0);

    for (int rr = 0; rr < ROUNDS; ++rr) {
        if (rr + 1 < ROUNDS) stageE(rr + 1);
        __builtin_amdgcn_sched_barrier(0);       // pin: stage glds issue first

        // V-wave: fold previous s-group's e (overlaps stage glds latency);
        // the round barrier (lgkmcnt(0)) ordered S's ds_writes before this.
        if (isV && (rr & 7) == 0 && rr > 0) vFold();

        const unsigned char* fb = sE + ((rr & 1) << 14);
        // ---- kstep 0 ----
        {
            W2 wn = loadW(rr, 1);
            s16x8 fe[8];
            #pragma unroll
            for (int nf = 0; nf < 8; ++nf)
                fe[nf] = *(const s16x8*)(fb + (nf << 11) + rowPart + (((laneQ) ^ laneX) << 4));
            __builtin_amdgcn_s_setprio(1);
            #pragma unroll
            for (int nf = 0; nf < 8; ++nf) {
                acc[0][nf] = __builtin_amdgcn_mfma_f32_16x16x32_bf16(wcur.r0, fe[nf], acc[0][nf], 0, 0, 0);
                acc[1][nf] = __builtin_amdgcn_mfma_f32_16x16x32_bf16(wcur.r1, fe[nf], acc[1][nf], 0, 0, 0);
            }
            __builtin_amdgcn_s_setprio(0);
            wcur = wn;
        }
        // ---- kstep 1 ----
        {
            W2 wn = (rr + 1 < ROUNDS) ? loadW(rr + 1, 0) : wcur;
            s16x8 fe[8];
            #pragma unroll
            for (int nf = 0; nf < 8; ++nf)
                fe[nf] = *(const s16x8*)(fb + (nf << 11) + rowPart + (((4 + laneQ) ^ laneX) << 4));
            __builtin_amdgcn_s_setprio(1);
            #pragma unroll
            for (int nf = 0; nf < 8; ++nf) {
                acc[0][nf] = __builtin_amdgcn_mfma_f32_16x16x32_bf16(wcur.r0, fe[nf], acc[0][nf], 0, 0, 0);
                acc[1][nf] = __builtin_amdgcn_mfma_f32_16x16x32_bf16(wcur.r1, fe[nf], acc[1][nf], 0, 0, 0);
            }
            __builtin_amdgcn_s_setprio(0);
            wcur = wn;
        }

        // S-wave group epilogue: e = exp(accS) -> den and bf16 e-buf
        // (scores ~N(0,0.45): |s|<~3.5, exp safe without max subtraction)
        if (!isV && (rr & 7) == 7) {
            #pragma unroll
            for (int j = 0; j < 8; ++j) {
                uint32_t wd[4];
                #pragma unroll
                for (int w2 = 0; w2 < 4; ++w2) {
                    const int v0 = j * 8 + w2 * 2, v1 = v0 + 1;
                    float e0 = __expf(acc[v0 >> 5][(v0 >> 2) & 7][v0 & 3]);
                    float e1 = __expf(acc[v1 >> 5][(v1 >> 2) & 7][v1 & 3]);
                    redAcc[v0 >> 5][v0 & 3] += e0;
                    redAcc[v1 >> 5][v1 & 3] += e1;
                    wd[w2] = (uint32_t)f2bf(e0) | ((uint32_t)f2bf(e1) << 16);
                }
                *(uint4*)(sE + ebufB + (lane << 7) + ((j ^ (lane & 7)) << 4)) =
                    make_uint4(wd[0], wd[1], wd[2], wd[3]);
            }
            #pragma unroll
            for (int mf = 0; mf < 2; ++mf)
                #pragma unroll
                for (int nf = 0; nf < 8; ++nf)
                    #pragma unroll
                    for (int r = 0; r < 4; ++r) acc[mf][nf][r] = 0.f;
        }

        // end-of-round sync: counted vmcnt keeps next-round kstep-0 W in
        // flight; lgkmcnt(0) drains the e-buf ds_writes for the V-read.
        __builtin_amdgcn_sched_barrier(0);
        asm volatile("s_waitcnt vmcnt(2) lgkmcnt(0)" ::: "memory");
        __builtin_amdgcn_s_barrier();
        __builtin_amdgcn_sched_barrier(0);
    }

    // final s-group fold for V-waves (after the last barrier)
    if (isV) vFold();

    // reduce the 16 s-columns spread over lane bits 0..3; each wave owns its
    // 32 L-rows completely -> no cross-wave reduce needed.
    const size_t obase = ((size_t)((b * NLT + lt) * NSC + sc)) * LTILE;
    float* dst = isV ? pnum : pden;
    #pragma unroll
    for (int mf = 0; mf < 2; ++mf)
        #pragma unroll
        for (int r = 0; r < 4; ++r) {
            float v = redAcc[mf][r];
            v += __shfl_xor(v, 1);
            v += __shfl_xor(v, 2);
            v += __shfl_xor(v, 4);
            v += __shfl_xor(v, 8);
            if ((lane & 15) == 0) {
                int row = h * 32 + mf * 16 + (lane >> 4) * 4 + r;
                dst[obase + row] = v;
            }
        }
}

// ---- combine s-chunk partials, divide, add b_cls ----
__global__ void finalize(const float* __restrict__ pnum, const float* __restrict__ pden,
                         const float* __restrict__ bcls, float* __restrict__ out) {
    int gid = blockIdx.x * 256 + threadIdx.x;
    if (gid >= B_ * L_) return;
    int b = gid / L_, l = gid - b * L_;
    int lt = l >> 6, row = l & 63;
    float n = 0.f, d = 0.f;
    #pragma unroll
    for (int s = 0; s < NSC; ++s) {
        size_t idx = ((size_t)((b * NLT + lt) * NSC + s)) * LTILE + row;
        n += pnum[idx];
        d += pden[idx];
    }
    out[gid] = n / d + bcls[l];
}

extern "C" void kernel_launch(void* const* d_in, const int* in_sizes, int n_in,
                              void* d_out, int out_size, void* d_ws, size_t ws_size,
                              hipStream_t stream) {
    (void)in_sizes; (void)n_in; (void)out_size; (void)ws_size;
    const float* enc  = (const float*)d_in[0];
    const float* Wa   = (const float*)d_in[1];
    // d_in[2] = b_attn: cancels in softmax over S — unused.
    const float* Wc   = (const float*)d_in[3];
    const float* bcls = (const float*)d_in[4];

    unsigned char* ws = (unsigned char*)d_ws;
    const size_t oEbt = 0;                          // B*S*C*2  = 16,777,216
    const size_t oWa  = oEbt + 16777216;            // L*C*2    =  9,135,104 (+pad)
    const size_t oWc  = oWa + 9136128;
    const size_t oPn  = oWc + 9136128;              // 8*140*4*64*4 = 1,146,880
    const size_t oPd  = oPn + 1146880;              // total ~37.3 MB

    unsigned short* ebt  = (unsigned short*)(ws + oEbt);
    unsigned short* waBf = (unsigned short*)(ws + oWa);
    unsigned short* wcBf = (unsigned short*)(ws + oWc);
    float* pnum = (float*)(ws + oPn);
    float* pden = (float*)(ws + oPd);

    prep<<<NEBLK + 2 * NWBLK, 256, 0, stream>>>(enc, ebt, Wa, waBf, Wc, wcBf);
    attn_main<<<NLT * 32, 256, 0, stream>>>(ebt, waBf, wcBf, pnum, pden);
    finalize<<<(B_ * L_ + 255) / 256, 256, 0, stream>>>(pnum, pden, bcls, (float*)d_out);
}

// Round 11
// 446.541 us; speedup vs baseline: 2.2039x; 1.0173x over previous
//
#include <hip/hip_runtime.h>
#include <hip/hip_bf16.h>
#include <stdint.h>

#define B_ 8
#define C_ 512
#define S_ 2048
#define L_ 8921
#define LTILE 256         // L rows per block (8 waves x 32)
#define NLT 35            // ceil(L/256); tail rows clamped, never read by finalize
#define BS 128            // s-rows per round-group (one acc lifetime)
#define SCHUNK 512        // s range per workgroup
#define NSC 4             // S / SCHUNK
#define BK 64             // k per round (2 ksteps of 32)
#define ROUNDS 32         // 4 s-tiles * 8 k-rounds

#define NW4 ((L_ * C_) / 4)          // 1,141,888 float4 quads per W array
#define NWBLK ((NW4 + 255) / 256)    // 4461 blocks per W array
#define NEBLK (B_ * 32 * 8)          // 2048 blocks for the E transpose

using f32x4 = __attribute__((ext_vector_type(4))) float;
using s16x8 = __attribute__((ext_vector_type(8))) short;   // 8 bf16 = 4 VGPRs

static __device__ __forceinline__ unsigned short f2bf(float f) {
    union { float f; uint32_t u; } a; a.f = f;
    uint32_t u = a.u;
    return (unsigned short)((u + 0x7fffu + ((u >> 16) & 1u)) >> 16);   // RTNE
}

// ---- fused prep: encoded transpose->bf16 + both W cvt in ONE launch ----
__global__ void prep(const float* __restrict__ enc, unsigned short* __restrict__ ebt,
                     const float* __restrict__ Wa, unsigned short* __restrict__ waBf,
                     const float* __restrict__ Wc, unsigned short* __restrict__ wcBf) {
    __shared__ float tile[64][65];
    const int x = blockIdx.x;
    const int t = threadIdx.x;

    if (x < NEBLK) {
        int ct = (x & 7) * 64;          // C/64 = 8
        int st = ((x >> 3) & 31) * 64;  // S/64 = 32
        int b  = x >> 8;
        const float* src = enc + (size_t)b * C_ * S_;
        #pragma unroll
        for (int it = 0; it < 16; ++it) {
            int idx = it * 256 + t;
            int rc = idx >> 6, rs = idx & 63;
            tile[rc][rs] = src[(size_t)(ct + rc) * S_ + st + rs];
        }
        __syncthreads();
        unsigned short* dst = ebt + (size_t)b * S_ * C_;
        #pragma unroll
        for (int it = 0; it < 4; ++it) {
            int idx = it * 256 + t;
            int rs  = idx >> 4;           // 0..63
            int rc4 = (idx & 15) << 2;    // 0,4,..,60
            ushort4 o;
            o.x = f2bf(tile[rc4 + 0][rs]);
            o.y = f2bf(tile[rc4 + 1][rs]);
            o.z = f2bf(tile[rc4 + 2][rs]);
            o.w = f2bf(tile[rc4 + 3][rs]);
            *(ushort4*)(dst + (size_t)(st + rs) * C_ + ct + rc4) = o;
        }
    } else {
        int wb = x - NEBLK;
        const float* src;
        unsigned short* dst;
        if (wb < NWBLK) { src = Wa; dst = waBf; }
        else            { src = Wc; dst = wcBf; wb -= NWBLK; }
        int i = wb * 256 + t;
        if (i < NW4) {
            float4 v = ((const float4*)src)[i];
            ushort4 o;
            o.x = f2bf(v.x); o.y = f2bf(v.y); o.z = f2bf(v.z); o.w = f2bf(v.w);
            ((ushort4*)dst)[i] = o;
        }
    }
}

// ---- fused scores/softmax/value main kernel ----
// R11: 8-wave block + depth-4 LDS ring + end-of-round staging.
// Theory: R8's ~39% both-waves-idle came from in-order vmcnt retirement --
// stage glds issued at round TOP put E's L3-miss latency (~450-900cy) in
// front of every W-consumption s_waitcnt. Here:
//  * 512 threads = 8 waves, each wave = R8's exact per-wave shape
//    (32 L-rows x both matrices x 128 s, acc 128 AGPR). LTILE=256 ->
//    E tile shared by 2x L-rows: glds per work HALVES; barriers per work
//    halve; grid 35x32=1120, 1 block/CU (VGPR-bound, 2 waves/SIMD).
//  * LDS ring of FOUR 16KB tiles (R1's measured-conflict-free layout:
//    128B rows, 8 chunks of 16B, chunk^(s&7), pre-swizzled glds source).
//    Round rr reads buf[rr&3]; stage(rr+3) issued at round END -> ~2.5
//    rounds of slack for L3 misses, and W loads sit AFTER older stages
//    by >=1 round in the vmem queue -> W-waits never drain a fresh stage.
//  * Barrier drains: vmcnt(8) steady (stage(rr+2)[2]+wfut[4]+stage(rr+3)[2]
//    newer than the stage(rr+1) we must retire); 6/4 at tail; none after
//    the last round. No full drain anywhere in the loop.
//  * No stagger (1 block/CU). setprio + sched_barrier pins kept.
__global__ __launch_bounds__(512, 2) void attn_main(
    const unsigned short* __restrict__ ebt,
    const unsigned short* __restrict__ wa,
    const unsigned short* __restrict__ wc,
    float* __restrict__ pnum, float* __restrict__ pden)
{
    __shared__ __align__(16) unsigned char sE[65536];   // 4 x 16KB ring

    const int tid  = threadIdx.x;
    const int lane = tid & 63;
    const int wave = tid >> 6;      // 0..7

    const int x  = blockIdx.x;
    const int lt = x >> 5;          // 32 consecutive blocks share one W tile
    const int rb = x & 31;
    const int b  = rb >> 2;
    const int sc = rb & 3;
    const int l0 = lt * LTILE;

    // per-lane W row offsets (element units), wave covers rows [wave*32, wave*32+32)
    int rowOff[2];
    #pragma unroll
    for (int mf = 0; mf < 2; ++mf) {
        int gl = l0 + wave * 32 + mf * 16 + (lane & 15);
        if (gl > L_ - 1) gl = L_ - 1;
        rowOff[mf] = gl * C_ + ((lane >> 4) << 3);
    }

    // E staging constants (R1's exact expressions)
    const size_t ebase = (size_t)b * S_ * C_;
    const int kgsrcE = (((lane & 7) ^ ((lane >> 3) & 7)) << 3);  // pre-swizzled src col
    // E frag read constants (R1's exact expressions)
    const int rowPart = (lane & 15) << 7;   // s_local * 128 bytes
    const int laneQ = lane >> 4;
    const int laneX = lane & 7;

    struct W4 { s16x8 a0, a1, c0, c1; };
    auto loadW = [&](int rr, int k) -> W4 {
        const int co = ((rr & 7) << 6) + (k << 5);
        W4 w;
        w.a0 = *(const s16x8*)(wa + rowOff[0] + co);
        w.a1 = *(const s16x8*)(wa + rowOff[1] + co);
        w.c0 = *(const s16x8*)(wc + rowOff[0] + co);
        w.c1 = *(const s16x8*)(wc + rowOff[1] + co);
        return w;
    };

    auto stageE = [&](int rr2) {
        const int kcol = (rr2 & 7) << 6;                    // 64-elem k base
        const int sBase = sc * SCHUNK + ((rr2 >> 3) << 7);  // s-tile*128
        unsigned char* dbase = sE + ((rr2 & 3) << 14);
        #pragma unroll
        for (int jj = 0; jj < 2; ++jj) {
            const int j = wave * 2 + jj;     // 0..15 over the 8 waves
            const int sg = sBase + j * 8 + (lane >> 3);
            const unsigned short* g = ebt + ebase + (size_t)sg * C_ + kcol + kgsrcE;
            __builtin_amdgcn_global_load_lds(
                (__attribute__((address_space(1))) void*)g,
                (__attribute__((address_space(3))) void*)(dbase + j * 1024),
                16, 0, 0);
        }
    };

    f32x4 accS[2][8], accV[2][8];
    #pragma unroll
    for (int mf = 0; mf < 2; ++mf)
        #pragma unroll
        for (int nf = 0; nf < 8; ++nf) {
            accS[mf][nf] = (f32x4){0.f, 0.f, 0.f, 0.f};
            accV[mf][nf] = (f32x4){0.f, 0.f, 0.f, 0.f};
        }
    float numAcc[2][4], denAcc[2][4];
    #pragma unroll
    for (int mf = 0; mf < 2; ++mf)
        #pragma unroll
        for (int r = 0; r < 4; ++r) { numAcc[mf][r] = 0.f; denAcc[mf][r] = 0.f; }

    // prologue: fill ring slots 0..2, full drain once, then steady state
    stageE(0);
    stageE(1);
    stageE(2);
    W4 wcur = loadW(0, 0);
    asm volatile("s_waitcnt vmcnt(0)" ::: "memory");
    __builtin_amdgcn_s_barrier();
    __builtin_amdgcn_sched_barrier(0);

    for (int rr = 0; rr < ROUNDS; ++rr) {
        const unsigned char* fb = sE + ((rr & 3) << 14);

        // ---- kstep 0 ----
        {
            W4 wnxt = loadW(rr, 1);
            s16x8 fe[8];
            #pragma unroll
            for (int nf = 0; nf < 8; ++nf)
                fe[nf] = *(const s16x8*)(fb + (nf << 11) + rowPart + (((laneQ) ^ laneX) << 4));
            __builtin_amdgcn_s_setprio(1);
            #pragma unroll
            for (int nf = 0; nf < 8; ++nf) {
                accS[0][nf] = __builtin_amdgcn_mfma_f32_16x16x32_bf16(wcur.a0, fe[nf], accS[0][nf], 0, 0, 0);
                accS[1][nf] = __builtin_amdgcn_mfma_f32_16x16x32_bf16(wcur.a1, fe[nf], accS[1][nf], 0, 0, 0);
                accV[0][nf] = __builtin_amdgcn_mfma_f32_16x16x32_bf16(wcur.c0, fe[nf], accV[0][nf], 0, 0, 0);
                accV[1][nf] = __builtin_amdgcn_mfma_f32_16x16x32_bf16(wcur.c1, fe[nf], accV[1][nf], 0, 0, 0);
            }
            __builtin_amdgcn_s_setprio(0);
            wcur = wnxt;
        }
        // ---- kstep 1 ----
        {
            W4 wfut = (rr + 1 < ROUNDS) ? loadW(rr + 1, 0) : wcur;
            s16x8 fe[8];
            #pragma unroll
            for (int nf = 0; nf < 8; ++nf)
                fe[nf] = *(const s16x8*)(fb + (nf << 11) + rowPart + (((4 + laneQ) ^ laneX) << 4));
            __builtin_amdgcn_s_setprio(1);
            #pragma unroll
            for (int nf = 0; nf < 8; ++nf) {
                accS[0][nf] = __builtin_amdgcn_mfma_f32_16x16x32_bf16(wcur.a0, fe[nf], accS[0][nf], 0, 0, 0);
                accS[1][nf] = __builtin_amdgcn_mfma_f32_16x16x32_bf16(wcur.a1, fe[nf], accS[1][nf], 0, 0, 0);
                accV[0][nf] = __builtin_amdgcn_mfma_f32_16x16x32_bf16(wcur.c0, fe[nf], accV[0][nf], 0, 0, 0);
                accV[1][nf] = __builtin_amdgcn_mfma_f32_16x16x32_bf16(wcur.c1, fe[nf], accV[1][nf], 0, 0, 0);
            }
            __builtin_amdgcn_s_setprio(0);
            wcur = wfut;
        }

        if ((rr & 7) == 7) {
            // softmax-accumulate epilogue for this 128-s tile
            // (scores ~N(0,0.45): |s|<~3.5, exp safe without max subtraction)
            #pragma unroll
            for (int mf = 0; mf < 2; ++mf)
                #pragma unroll
                for (int nf = 0; nf < 8; ++nf)
                    #pragma unroll
                    for (int r = 0; r < 4; ++r) {
                        float e = __expf(accS[mf][nf][r]);
                        denAcc[mf][r] += e;
                        numAcc[mf][r] += e * accV[mf][nf][r];
                        accS[mf][nf][r] = 0.f;
                        accV[mf][nf][r] = 0.f;
                    }
        }

        // ---- end of round: stage(rr+3) into the slot freed last round ----
        if (rr + 3 < ROUNDS) stageE(rr + 3);
        __builtin_amdgcn_sched_barrier(0);
        if (rr + 1 < ROUNDS) {
            // drain exactly to "stage(rr+1) retired" (ring slot for next
            // round): newer ops = stage(rr+2)[2] + wfut[4] + stage(rr+3)[2]
            if (rr + 3 < ROUNDS)      asm volatile("s_waitcnt vmcnt(8)" ::: "memory");
            else if (rr + 2 < ROUNDS) asm volatile("s_waitcnt vmcnt(6)" ::: "memory");
            else                      asm volatile("s_waitcnt vmcnt(4)" ::: "memory");
            __builtin_amdgcn_s_barrier();
            __builtin_amdgcn_sched_barrier(0);
        }
    }

    // reduce the 16 s-columns spread over lane bits 0..3; each wave owns its
    // 32 L-rows completely (nf covered the full 128-s span) -> no LDS reduce.
    const size_t obase = ((size_t)((b * NLT + lt) * NSC + sc)) * LTILE;
    #pragma unroll
    for (int mf = 0; mf < 2; ++mf)
        #pragma unroll
        for (int r = 0; r < 4; ++r) {
            float n = numAcc[mf][r], d = denAcc[mf][r];
            n += __shfl_xor(n, 1);  d += __shfl_xor(d, 1);
            n += __shfl_xor(n, 2);  d += __shfl_xor(d, 2);
            n += __shfl_xor(n, 4);  d += __shfl_xor(d, 4);
            n += __shfl_xor(n, 8);  d += __shfl_xor(d, 8);
            if ((lane & 15) == 0) {
                int row = wave * 32 + mf * 16 + (lane >> 4) * 4 + r;
                pnum[obase + row] = n;
                pden[obase + row] = d;
            }
        }
}

// ---- combine s-chunk partials, divide, add b_cls ----
__global__ void finalize(const float* __restrict__ pnum, const float* __restrict__ pden,
                         const float* __restrict__ bcls, float* __restrict__ out) {
    int gid = blockIdx.x * 256 + threadIdx.x;
    if (gid >= B_ * L_) return;
    int b = gid / L_, l = gid - b * L_;
    int lt = l >> 8, row = l & 255;
    float n = 0.f, d = 0.f;
    #pragma unroll
    for (int s = 0; s < NSC; ++s) {
        size_t idx = ((size_t)((b * NLT + lt) * NSC + s)) * LTILE + row;
        n += pnum[idx];
        d += pden[idx];
    }
    out[gid] = n / d + bcls[l];
}

extern "C" void kernel_launch(void* const* d_in, const int* in_sizes, int n_in,
                              void* d_out, int out_size, void* d_ws, size_t ws_size,
                              hipStream_t stream) {
    (void)in_sizes; (void)n_in; (void)out_size; (void)ws_size;
    const float* enc  = (const float*)d_in[0];
    const float* Wa   = (const float*)d_in[1];
    // d_in[2] = b_attn: cancels in softmax over S — unused.
    const float* Wc   = (const float*)d_in[3];
    const float* bcls = (const float*)d_in[4];

    unsigned char* ws = (unsigned char*)d_ws;
    const size_t oEbt = 0;                          // B*S*C*2  = 16,777,216
    const size_t oWa  = oEbt + 16777216;            // L*C*2    =  9,135,104 (+pad)
    const size_t oWc  = oWa + 9136128;
    const size_t oPn  = oWc + 9136128;              // 8*35*4*256*4 = 1,146,880
    const size_t oPd  = oPn + 1146880;              // total ~37.3 MB

    unsigned short* ebt  = (unsigned short*)(ws + oEbt);
    unsigned short* waBf = (unsigned short*)(ws + oWa);
    unsigned short* wcBf = (unsigned short*)(ws + oWc);
    float* pnum = (float*)(ws + oPn);
    float* pden = (float*)(ws + oPd);

    prep<<<NEBLK + 2 * NWBLK, 256, 0, stream>>>(enc, ebt, Wa, waBf, Wc, wcBf);
    attn_main<<<NLT * 32, 512, 0, stream>>>(ebt, waBf, wcBf, pnum, pden);
    finalize<<<(B_ * L_ + 255) / 256, 256, 0, stream>>>(pnum, pden, bcls, (float*)d_out);
}